// Round 11
// baseline (35377.203 us; speedup 1.0000x reference)
//
#include <hip/hip_runtime.h>
#include <hip/hip_bf16.h>

#define H      1024
#define IN_DIM 512
#define OD     512
#define T_LEN  16384
#define NWG    64     // 8 waves/WG: wave 0 = global reader, waves 1-7 = LDS consumers
#define NREP   8      // value-array replicas (pollers/replica = 64/8 = 8)
#define RS     (H + 64)        // replica stride in floats (256B pad)
#define PSTRIDE (NREP * RS)    // parity stride in floats

typedef unsigned long long u64;
typedef unsigned int u32;

__device__ __forceinline__ u32 pack_bf(float lo, float hi) {
    u32 a = __float_as_uint(lo); a = (a + 0x7fffu + ((a >> 16) & 1u)) >> 16;          // RNE -> [15:0]
    u32 b = __float_as_uint(hi); b = (b + 0x7fffu + ((b >> 16) & 1u)) & 0xffff0000u;  // RNE -> [31:16]
    return a | b;
}
__device__ __forceinline__ float bf_lo(u32 pk) { return __uint_as_float(pk << 16); }
__device__ __forceinline__ float bf_hi(u32 pk) { return __uint_as_float(pk & 0xffff0000u); }

// vals[parity][rep][RS]: f32 h-state, mantissa LSB = lap bit ((tag>>1)&1).
// tag T == h after T steps (h_0 = 0). Consumer iter t expects lap (t>>1)&1 in
// parity t&1; producer of tag t+1 writes parity (t+1)&1 with lap ((t+1)>>1)&1.
// Machine shape: 64 WGs x 512 threads (8 waves). Global wave gw = wg*8+wave
// owns units {2gw, 2gw+1}. After the 6-acc butterfly ALL lanes hold both
// units' sums -> every lane computes both gates; lanes 0..NREP-1 publish the
// wave's u64 (2 packed f32+lap) via __hip_atomic_store RELAXED/AGENT — the
// R5-R9-proven LLC-visible path. (R10 lesson: a PLAIN store can sit dirty in
// the producer XCD's write-back L2 forever -> cross-XCD deadlock. Publishes
// MUST be agent-scope atomics.) A 64B pair-line (16 units) is written by 8
// waves of the SAME WG/CU -> stores land close in time, line settles fast.
// Ingest: wave 0 polls its replica (8 coalesced u64 agent loads = whole 4KB,
// u64 idx k*64+lane = units {2l,2l+1}+128k), relays via LDS; waves 1-7 spin
// on LDS lap bits. Race-freedom (tag monotonicity): any publish of t+1
// data-depends (butterfly) on that wave's full ingest of t; overwrite of a
// parity slot (global or LDS) with t+2 transitively requires all t+1
// publishes, hence all parity-t reads complete. Per-u64 lap checks make
// partially-written state safe. LDS parity0 init = 0 (h_0 valid for t=0),
// parity1 init lap=1 (blocks t=1).
__global__ __launch_bounds__(512, 2)
void gru_rec_kernel(const float* __restrict__ X,
                    const float* __restrict__ Wih,
                    const float* __restrict__ Whh,
                    const float* __restrict__ bih,
                    const float* __restrict__ bhh,
                    float* __restrict__ hs,
                    u32* __restrict__ vals)
{
    __shared__ u64 lsh[2][8][64];   // 8 KB: [parity][k][lane]

    const int tid  = threadIdx.x;
    const int wave = tid >> 6;           // 0..7
    const int lane = tid & 63;
    const int wg   = blockIdx.x;
    const int gw   = wg * 8 + wave;      // 0..511; units 2gw, 2gw+1
    const int u0   = 2 * gw, u1 = 2 * gw + 1;

    // ---- weights -> registers, bf16-packed; lane l owns cols {2l,2l+1}+128k ----
    // rows: 0=r*u0 1=r*u1 2=z*u0 3=z*u1 4=n*u0 5=n*u1
    u32 whh_r[6][8];
    u32 wih_r[6][4];
    #pragma unroll
    for (int g = 0; g < 3; ++g) {
        #pragma unroll
        for (int j = 0; j < 2; ++j) {
            const float* wr = Whh + (size_t)(g * H + 2 * gw + j) * H;
            #pragma unroll
            for (int k = 0; k < 8; ++k)
                whh_r[g * 2 + j][k] = pack_bf(wr[2 * lane + 128 * k], wr[2 * lane + 1 + 128 * k]);
            const float* wx = Wih + (size_t)(g * H + 2 * gw + j) * IN_DIM;
            #pragma unroll
            for (int k = 0; k < 4; ++k)
                wih_r[g * 2 + j][k] = pack_bf(wx[2 * lane + 128 * k], wx[2 * lane + 1 + 128 * k]);
        }
    }
    const float bxr0 = bih[u0], bxz0 = bih[H + u0], bxn0 = bih[2 * H + u0];
    const float bhr0 = bhh[u0], bhz0 = bhh[H + u0], bhn0 = bhh[2 * H + u0];
    const float bxr1 = bih[u1], bxz1 = bih[H + u1], bxn1 = bih[2 * H + u1];
    const float bhr1 = bhh[u1], bhz1 = bhh[H + u1], bhn1 = bhh[2 * H + u1];

    // ---- LDS init: parity0 = 0 (h_0, lap 0, valid for t=0); parity1 lap = 1 ----
    {
        u32* lp = (u32*)lsh;
        for (int i = tid; i < 2048; i += 512) lp[i] = (i < 1024) ? 0u : 1u;
    }
    __syncthreads();

    // ---- x row t=0 + partials (prologue) ----
    float xw[8];
    #pragma unroll
    for (int k = 0; k < 4; ++k) {
        float2 vv = *(const float2*)(X + 2 * lane + 128 * k);
        xw[2 * k] = vv.x; xw[2 * k + 1] = vv.y;
    }
    float pxr0 = 0.f, pxr1 = 0.f, pxz0 = 0.f, pxz1 = 0.f, pxn0 = 0.f, pxn1 = 0.f;
    {
        float n0 = 0.f, n1 = 0.f;
        #pragma unroll
        for (int k = 0; k < 4; ++k) {
            const float x0 = xw[2 * k], x1 = xw[2 * k + 1];
            pxr0 += bf_lo(wih_r[0][k]) * x0 + bf_hi(wih_r[0][k]) * x1;
            pxr1 += bf_lo(wih_r[1][k]) * x0 + bf_hi(wih_r[1][k]) * x1;
            pxz0 += bf_lo(wih_r[2][k]) * x0 + bf_hi(wih_r[2][k]) * x1;
            pxz1 += bf_lo(wih_r[3][k]) * x0 + bf_hi(wih_r[3][k]) * x1;
            n0   += bf_lo(wih_r[4][k]) * x0 + bf_hi(wih_r[4][k]) * x1;
            n1   += bf_lo(wih_r[5][k]) * x0 + bf_hi(wih_r[5][k]) * x1;
        }
        #pragma unroll
        for (int s = 32; s; s >>= 1) {
            n0 += __shfl_xor(n0, s, 64);
            n1 += __shfl_xor(n1, s, 64);
        }
        pxn0 = n0; pxn1 = n1;
    }

    const int rep = wg & (NREP - 1);
    float hmine0 = 0.f, hmine1 = 0.f;

    #pragma unroll 1
    for (int t = 0; t < T_LEN; ++t) {
        const u32 lapexp = (u32)((t >> 1) & 1);
        const int p = t & 1;
        u64 v[8];

        if (wave == 0) {
            // ---- global spin: 8 coalesced u64 agent loads (detect == data) ----
            const u64* pb = (const u64*)(vals + (size_t)p * PSTRIDE
                                              + (size_t)rep * RS) + lane;
            for (;;) {
                #pragma unroll
                for (int k = 0; k < 8; ++k)
                    v[k] = __hip_atomic_load(pb + 64 * k, __ATOMIC_RELAXED,
                                             __HIP_MEMORY_SCOPE_AGENT);
                u32 bad = 0;
                #pragma unroll
                for (int k = 0; k < 8; ++k)
                    bad |= ((u32)v[k] ^ lapexp) | ((u32)(v[k] >> 32) ^ lapexp);
                if (!(bad & 1u)) break;
            }
            // relay to the WG ASAP (per-u64 ds_write; laps make partial state safe)
            #pragma unroll
            for (int k = 0; k < 8; ++k)
                __hip_atomic_store(&lsh[p][k][lane], v[k], __ATOMIC_RELAXED,
                                   __HIP_MEMORY_SCOPE_WORKGROUP);
        } else {
            // ---- LDS spin ----
            for (;;) {
                u32 bad = 0;
                #pragma unroll
                for (int k = 0; k < 8; ++k) {
                    v[k] = __hip_atomic_load(&lsh[p][k][lane], __ATOMIC_RELAXED,
                                             __HIP_MEMORY_SCOPE_WORKGROUP);
                    bad |= ((u32)v[k] ^ lapexp) | ((u32)(v[k] >> 32) ^ lapexp);
                }
                if (!(bad & 1u)) break;
            }
        }

        // rotating coalesced store of PREVIOUS hs row (v = h_t = reference hs[t-1])
        if (t && wave == 1 && wg == ((t - 1) & (NWG - 1))) {
            u64* dst = (u64*)(hs + (size_t)(t - 1) * H) + lane;
            #pragma unroll
            for (int k = 0; k < 8; ++k) dst[64 * k] = v[k];
        }

        // issue next-x loads now: latency hides under h-partials/butterfly/gates
        float xn2[8];
        {
            const int tn = (t + 1 < T_LEN) ? (t + 1) : t;
            const float* xp = X + (size_t)tn * IN_DIM;
            #pragma unroll
            for (int k = 0; k < 4; ++k) {
                float2 vv = *(const float2*)(xp + 2 * lane + 128 * k);
                xn2[2 * k] = vv.x; xn2[2 * k + 1] = vv.y;
            }
        }

        // ---- h partials: 6 dots (2 units x 3 gates), lane-local values ----
        float a0 = pxr0, a1 = pxr1, a2 = pxz0, a3 = pxz1, a4 = 0.f, a5 = 0.f;
        #pragma unroll
        for (int k = 0; k < 8; ++k) {
            const float h0 = __uint_as_float((u32)v[k]);
            const float h1 = __uint_as_float((u32)(v[k] >> 32));
            a0 += bf_lo(whh_r[0][k]) * h0 + bf_hi(whh_r[0][k]) * h1;
            a1 += bf_lo(whh_r[1][k]) * h0 + bf_hi(whh_r[1][k]) * h1;
            a2 += bf_lo(whh_r[2][k]) * h0 + bf_hi(whh_r[2][k]) * h1;
            a3 += bf_lo(whh_r[3][k]) * h0 + bf_hi(whh_r[3][k]) * h1;
            a4 += bf_lo(whh_r[4][k]) * h0 + bf_hi(whh_r[4][k]) * h1;
            a5 += bf_lo(whh_r[5][k]) * h0 + bf_hi(whh_r[5][k]) * h1;
        }
        #pragma unroll
        for (int s = 32; s; s >>= 1) {
            a0 += __shfl_xor(a0, s, 64);
            a1 += __shfl_xor(a1, s, 64);
            a2 += __shfl_xor(a2, s, 64);
            a3 += __shfl_xor(a3, s, 64);
            a4 += __shfl_xor(a4, s, 64);
            a5 += __shfl_xor(a5, s, 64);
        }

        // ---- gates for BOTH units on all lanes; one atomic u64 publish/replica ----
        const float r0 = 1.f / (1.f + __expf(-(a0 + bxr0 + bhr0)));
        const float z0 = 1.f / (1.f + __expf(-(a2 + bxz0 + bhz0)));
        const float e0 = __expf(2.f * (pxn0 + bxn0 + r0 * (a4 + bhn0)));
        const float n0 = 1.f - 2.f / (e0 + 1.f);
        const float h0 = (1.f - z0) * n0 + z0 * hmine0;

        const float r1 = 1.f / (1.f + __expf(-(a1 + bxr1 + bhr1)));
        const float z1 = 1.f / (1.f + __expf(-(a3 + bxz1 + bhz1)));
        const float e1 = __expf(2.f * (pxn1 + bxn1 + r1 * (a5 + bhn1)));
        const float n1 = 1.f - 2.f / (e1 + 1.f);
        const float h1 = (1.f - z1) * n1 + z1 * hmine1;

        const u32 lapw = (u32)(((t + 1) >> 1) & 1);
        const u32 bits0 = (__float_as_uint(h0) & ~1u) | lapw;
        const u32 bits1 = (__float_as_uint(h1) & ~1u) | lapw;
        hmine0 = __uint_as_float(bits0);
        hmine1 = __uint_as_float(bits1);
        const u64 pk = ((u64)bits1 << 32) | (u64)bits0;
        if (lane < NREP)
            __hip_atomic_store((u64*)(vals + (size_t)((t + 1) & 1) * PSTRIDE
                                           + (size_t)lane * RS) + gw,
                               pk, __ATOMIC_RELAXED, __HIP_MEMORY_SCOPE_AGENT);

        if (t == T_LEN - 1 && lane == 0)
            ((u64*)(hs + (size_t)t * H))[gw] = pk;   // final row (tag T never re-read)

        // ---- epilogue: x partials for t+1 (hidden under the next spin) ----
        {
            float xr0 = 0.f, xr1 = 0.f, xz0 = 0.f, xz1 = 0.f, n0e = 0.f, n1e = 0.f;
            #pragma unroll
            for (int k = 0; k < 4; ++k) {
                const float x0 = xn2[2 * k], x1 = xn2[2 * k + 1];
                xr0 += bf_lo(wih_r[0][k]) * x0 + bf_hi(wih_r[0][k]) * x1;
                xr1 += bf_lo(wih_r[1][k]) * x0 + bf_hi(wih_r[1][k]) * x1;
                xz0 += bf_lo(wih_r[2][k]) * x0 + bf_hi(wih_r[2][k]) * x1;
                xz1 += bf_lo(wih_r[3][k]) * x0 + bf_hi(wih_r[3][k]) * x1;
                n0e += bf_lo(wih_r[4][k]) * x0 + bf_hi(wih_r[4][k]) * x1;
                n1e += bf_lo(wih_r[5][k]) * x0 + bf_hi(wih_r[5][k]) * x1;
            }
            #pragma unroll
            for (int s = 32; s; s >>= 1) {
                n0e += __shfl_xor(n0e, s, 64);
                n1e += __shfl_xor(n1e, s, 64);
            }
            pxr0 = xr0; pxr1 = xr1; pxz0 = xz0; pxz1 = xz1; pxn0 = n0e; pxn1 = n1e;
        }
    }
}

// out[m,n] = sum_k hs[m,k] * Wfc[n,k] + bfc[n]   (M=16384, N=512, K=1024)
#define BM 64
#define BN 64
#define BK 16
__global__ __launch_bounds__(256)
void fc_kernel(const float* __restrict__ A, const float* __restrict__ B,
               const float* __restrict__ bias, float* __restrict__ C)
{
    __shared__ float As[BK][BM + 4];
    __shared__ float Bs[BK][BN + 4];
    const int tid = threadIdx.x;
    const int m0 = blockIdx.y * BM, n0 = blockIdx.x * BN;
    const int tx = tid & 15, ty = tid >> 4;
    float acc[4][4] = {};
    const int r = tid >> 2, c = (tid & 3) << 2;
    for (int k0 = 0; k0 < H; k0 += BK) {
        float4 va = *(const float4*)(A + (size_t)(m0 + r) * H + (k0 + c));
        As[c + 0][r] = va.x; As[c + 1][r] = va.y; As[c + 2][r] = va.z; As[c + 3][r] = va.w;
        float4 vb = *(const float4*)(B + (size_t)(n0 + r) * H + (k0 + c));
        Bs[c + 0][r] = vb.x; Bs[c + 1][r] = vb.y; Bs[c + 2][r] = vb.z; Bs[c + 3][r] = vb.w;
        __syncthreads();
        #pragma unroll
        for (int kk = 0; kk < BK; ++kk) {
            float4 a4 = *(const float4*)&As[kk][ty * 4];
            float4 b4 = *(const float4*)&Bs[kk][tx * 4];
            const float av[4] = {a4.x, a4.y, a4.z, a4.w};
            const float bv[4] = {b4.x, b4.y, b4.z, b4.w};
            #pragma unroll
            for (int i = 0; i < 4; ++i)
                #pragma unroll
                for (int j = 0; j < 4; ++j)
                    acc[i][j] += av[i] * bv[j];
        }
        __syncthreads();
    }
    #pragma unroll
    for (int i = 0; i < 4; ++i) {
        const int m = m0 + ty * 4 + i;
        #pragma unroll
        for (int j = 0; j < 4; ++j) {
            const int n = n0 + tx * 4 + j;
            C[(size_t)m * OD + n] = acc[i][j] + bias[n];
        }
    }
}

extern "C" void kernel_launch(void* const* d_in, const int* in_sizes, int n_in,
                              void* d_out, int out_size, void* d_ws, size_t ws_size,
                              hipStream_t stream) {
    const float* X   = (const float*)d_in[0];
    const float* Wih = (const float*)d_in[1];
    const float* Whh = (const float*)d_in[2];
    const float* bih = (const float*)d_in[3];
    const float* bhh = (const float*)d_in[4];
    const float* Wfc = (const float*)d_in[5];
    const float* bfc = (const float*)d_in[6];
    float* out = (float*)d_out;

    float* hs  = (float*)d_ws;                                   // 64 MB
    u32*  vals = (u32*)((char*)d_ws + (size_t)T_LEN * H * 4);    // 2*PSTRIDE*4 ~ 70 KB

    // parity0: h_0 = 0.0, lap 0 (valid for t=0). parity1: 0x01 bytes -> lap 1
    // blocks t=1 consumers until the real h_1 arrives.
    hipMemsetAsync(vals, 0x00, (size_t)PSTRIDE * 4, stream);
    hipMemsetAsync(vals + PSTRIDE, 0x01, (size_t)PSTRIDE * 4, stream);

    void* args[] = { (void*)&X, (void*)&Wih, (void*)&Whh, (void*)&bih,
                     (void*)&bhh, (void*)&hs, (void*)&vals };
    hipError_t e = hipLaunchCooperativeKernel((const void*)gru_rec_kernel,
                                              dim3(NWG), dim3(512), args, 0, stream);
    if (e != hipSuccess) {
        gru_rec_kernel<<<dim3(NWG), dim3(512), 0, stream>>>(X, Wih, Whh, bih, bhh, hs, vals);
    }

    dim3 fgrid(OD / BN, T_LEN / BM);
    fc_kernel<<<fgrid, dim3(256), 0, stream>>>(hs, Wfc, bfc, out);
}

// Round 12
// 28592.877 us; speedup vs baseline: 1.2373x; 1.2373x over previous
//
#include <hip/hip_runtime.h>
#include <hip/hip_bf16.h>

#define H      1024
#define IN_DIM 512
#define OD     512
#define T_LEN  16384
#define NWG    256    // 4 independent waves per WG; global wave == hidden unit
#define NREP   16     // value-array replicas (contention/write-amp balance)
#define RS     (H + 64)        // replica stride in floats (256B pad)
#define PSTRIDE (NREP * RS)    // parity stride in floats

typedef unsigned long long u64;
typedef unsigned int u32;

__device__ __forceinline__ u32 pack_bf(float lo, float hi) {
    u32 a = __float_as_uint(lo); a = (a + 0x7fffu + ((a >> 16) & 1u)) >> 16;          // RNE -> [15:0]
    u32 b = __float_as_uint(hi); b = (b + 0x7fffu + ((b >> 16) & 1u)) & 0xffff0000u;  // RNE -> [31:16]
    return a | b;
}
__device__ __forceinline__ float bf_lo(u32 pk) { return __uint_as_float(pk << 16); }
__device__ __forceinline__ float bf_hi(u32 pk) { return __uint_as_float(pk & 0xffff0000u); }

// R7 structure (proven 28.6 ms) + R8's schedule fix, un-confounded:
// vals[parity][rep][RS]: f32 h-state, mantissa LSB = lap bit ((tag>>1)&1).
// tag T == h after T steps (h_0 = 0). Consumer iter t reads parity t&1
// expecting lap (t>>1)&1; producer of tag t+1 writes parity (t+1)&1 with lap
// ((t+1)>>1)&1. Initial: parity0 = 0x00 bytes (h_0, lap 0, valid for t=0);
// parity1 = 0x01 bytes (lap 1, blocks t=1 until real h_1).
// Race-freedom (tag monotonicity): publish(t+1) data-depends (butterfly) on
// all 64 lanes' lap-verified ingest of tag t; overwrite of a parity slot
// (tag t+2) requires its producer to have ingested ALL tag-t+1 values, which
// requires every wave to have published t+1, hence ingested t.
// Transport: lane l owns h cols {2l,2l+1}+128k; poll instruction k is
// 64 lanes x 8B = 512B contiguous. Loads/stores are RELAXED/AGENT atomics
// (LLC-coherent; R10 lesson: plain stores sit dirty in XCD L2 -> deadlock).
// SCHEDULE FIX vs R7: the spin region contains ONLY the 8 poll loads (no
// x-prefetch in the vmcnt drain); next-x loads issue after detect (latency
// hides under h-partials/butterfly/gates); x-partials for t+1 computed in
// the epilogue after publish (in the arrival shadow of other waves' stores).
__global__ __launch_bounds__(256, 1)
void gru_rec_kernel(const float* __restrict__ X,
                    const float* __restrict__ Wih,
                    const float* __restrict__ Whh,
                    const float* __restrict__ bih,
                    const float* __restrict__ bhh,
                    float* __restrict__ hs,
                    u32* __restrict__ vals)
{
    const int tid  = threadIdx.x;
    const int wave = tid >> 6;
    const int lane = tid & 63;
    const int wg   = blockIdx.x;
    const int gw   = wg * 4 + wave;        // global wave == hidden unit u
    const int u    = gw;

    // ---- weights -> registers, bf16-packed; lane l owns cols {2l,2l+1}+128k ----
    u32 whh_r[3][8];   // h-part: k = 0..7
    u32 wih_r[3][4];   // x-part: k = 0..3
    #pragma unroll
    for (int g = 0; g < 3; ++g) {
        const float* wr = Whh + (size_t)(g * H + u) * H;
        #pragma unroll
        for (int k = 0; k < 8; ++k)
            whh_r[g][k] = pack_bf(wr[2 * lane + 128 * k], wr[2 * lane + 1 + 128 * k]);
        const float* wx = Wih + (size_t)(g * H + u) * IN_DIM;
        #pragma unroll
        for (int k = 0; k < 4; ++k)
            wih_r[g][k] = pack_bf(wx[2 * lane + 128 * k], wx[2 * lane + 1 + 128 * k]);
    }
    const float bxr = bih[u], bxz = bih[H + u], bxn = bih[2 * H + u];
    const float bhr = bhh[u], bhz = bhh[H + u], bhn = bhh[2 * H + u];

    // ---- prologue: x partials for t=0 ----
    float pxr = 0.f, pxz = 0.f, pxns = 0.f;
    {
        float xq[8];
        #pragma unroll
        for (int k = 0; k < 4; ++k) {
            float2 vv = *(const float2*)(X + 2 * lane + 128 * k);
            xq[2 * k] = vv.x; xq[2 * k + 1] = vv.y;
        }
        float xn = 0.f;
        #pragma unroll
        for (int k = 0; k < 4; ++k) {
            const float x0 = xq[2 * k], x1 = xq[2 * k + 1];
            pxr += bf_lo(wih_r[0][k]) * x0 + bf_hi(wih_r[0][k]) * x1;
            pxz += bf_lo(wih_r[1][k]) * x0 + bf_hi(wih_r[1][k]) * x1;
            xn  += bf_lo(wih_r[2][k]) * x0 + bf_hi(wih_r[2][k]) * x1;
        }
        #pragma unroll
        for (int s = 32; s; s >>= 1) xn += __shfl_xor(xn, s, 64);
        pxns = xn;
    }

    const int rep = gw & (NREP - 1);       // my replica (spreads WG's waves too)
    float hmine = 0.f;                     // this wave's own h_t[u], full precision

    #pragma unroll 1
    for (int t = 0; t < T_LEN; ++t) {
        const u32 lapexp = (u32)((t >> 1) & 1);

        // ---- spin: ONLY the 8 coalesced u64 agent loads in the vmcnt drain ----
        const u64* pb = (const u64*)(vals + (size_t)(t & 1) * PSTRIDE
                                          + (size_t)rep * RS) + lane;
        u64 v[8];
        for (;;) {
            #pragma unroll
            for (int k = 0; k < 8; ++k)
                v[k] = __hip_atomic_load(pb + 64 * k, __ATOMIC_RELAXED,
                                         __HIP_MEMORY_SCOPE_AGENT);
            u32 bad = 0;
            #pragma unroll
            for (int k = 0; k < 8; ++k)
                bad |= ((u32)v[k] ^ lapexp) | ((u32)(v[k] >> 32) ^ lapexp);
            if (!(bad & 1u)) break;
        }

        // rotating coalesced store of PREVIOUS hs row (v = h_t = reference hs[t-1]);
        // issued here so its store-acks retire during compute, before next spin
        if (t && gw == ((t - 1) & (H - 1))) {
            u64* dst = (u64*)(hs + (size_t)(t - 1) * H) + lane;
            #pragma unroll
            for (int k = 0; k < 8; ++k) dst[64 * k] = v[k];
        }

        // issue next-x loads now: latency hides under h-partials/butterfly/gates
        float xq[8];
        {
            const int tn = (t + 1 < T_LEN) ? (t + 1) : t;
            const float* xp = X + (size_t)tn * IN_DIM;
            #pragma unroll
            for (int k = 0; k < 4; ++k) {
                float2 vv = *(const float2*)(xp + 2 * lane + 128 * k);
                xq[2 * k] = vv.x; xq[2 * k + 1] = vv.y;
            }
        }

        // ---- h partials (lane-local values; only sums cross lanes) ----
        float ar = pxr, az = pxz, anh = 0.f;
        #pragma unroll
        for (int k = 0; k < 8; ++k) {
            const float h0 = __uint_as_float((u32)v[k]);
            const float h1 = __uint_as_float((u32)(v[k] >> 32));
            ar  += bf_lo(whh_r[0][k]) * h0 + bf_hi(whh_r[0][k]) * h1;
            az  += bf_lo(whh_r[1][k]) * h0 + bf_hi(whh_r[1][k]) * h1;
            anh += bf_lo(whh_r[2][k]) * h0 + bf_hi(whh_r[2][k]) * h1;
        }
        #pragma unroll
        for (int s = 32; s; s >>= 1) {
            ar  += __shfl_xor(ar,  s, 64);
            az  += __shfl_xor(az,  s, 64);
            anh += __shfl_xor(anh, s, 64);
        }

        // ---- gates (all lanes redundantly) + one-instruction NREP publish ----
        const float r = 1.f / (1.f + __expf(-(ar + bxr + bhr)));
        const float z = 1.f / (1.f + __expf(-(az + bxz + bhz)));
        const float e2 = __expf(2.f * (pxns + bxn + r * (anh + bhn)));
        const float n = 1.f - 2.f / (e2 + 1.f);   // tanh
        const float hnew = (1.f - z) * n + z * hmine;
        const u32 lapw = (u32)(((t + 1) >> 1) & 1);
        const u32 bits = (__float_as_uint(hnew) & ~1u) | lapw;
        hmine = __uint_as_float(bits);
        if (lane < NREP)
            __hip_atomic_store(vals + (size_t)((t + 1) & 1) * PSTRIDE
                                    + (size_t)lane * RS + u,
                               bits, __ATOMIC_RELAXED, __HIP_MEMORY_SCOPE_AGENT);
        if (t == T_LEN - 1 && lane == 0)
            hs[(size_t)t * H + u] = hmine;   // final row: tag T_LEN never re-read

        // ---- epilogue: x partials for t+1 (post-publish, in the arrival shadow) ----
        {
            float xr2 = 0.f, xz2 = 0.f, xn3 = 0.f;
            #pragma unroll
            for (int k = 0; k < 4; ++k) {
                const float x0 = xq[2 * k], x1 = xq[2 * k + 1];
                xr2 += bf_lo(wih_r[0][k]) * x0 + bf_hi(wih_r[0][k]) * x1;
                xz2 += bf_lo(wih_r[1][k]) * x0 + bf_hi(wih_r[1][k]) * x1;
                xn3 += bf_lo(wih_r[2][k]) * x0 + bf_hi(wih_r[2][k]) * x1;
            }
            #pragma unroll
            for (int s = 32; s; s >>= 1) xn3 += __shfl_xor(xn3, s, 64);
            pxr = xr2; pxz = xz2; pxns = xn3;
        }
    }
}

// out[m,n] = sum_k hs[m,k] * Wfc[n,k] + bfc[n]   (M=16384, N=512, K=1024)
#define BM 64
#define BN 64
#define BK 16
__global__ __launch_bounds__(256)
void fc_kernel(const float* __restrict__ A, const float* __restrict__ B,
               const float* __restrict__ bias, float* __restrict__ C)
{
    __shared__ float As[BK][BM + 4];
    __shared__ float Bs[BK][BN + 4];
    const int tid = threadIdx.x;
    const int m0 = blockIdx.y * BM, n0 = blockIdx.x * BN;
    const int tx = tid & 15, ty = tid >> 4;
    float acc[4][4] = {};
    const int r = tid >> 2, c = (tid & 3) << 2;
    for (int k0 = 0; k0 < H; k0 += BK) {
        float4 va = *(const float4*)(A + (size_t)(m0 + r) * H + (k0 + c));
        As[c + 0][r] = va.x; As[c + 1][r] = va.y; As[c + 2][r] = va.z; As[c + 3][r] = va.w;
        float4 vb = *(const float4*)(B + (size_t)(n0 + r) * H + (k0 + c));
        Bs[c + 0][r] = vb.x; Bs[c + 1][r] = vb.y; Bs[c + 2][r] = vb.z; Bs[c + 3][r] = vb.w;
        __syncthreads();
        #pragma unroll
        for (int kk = 0; kk < BK; ++kk) {
            float4 a4 = *(const float4*)&As[kk][ty * 4];
            float4 b4 = *(const float4*)&Bs[kk][tx * 4];
            const float av[4] = {a4.x, a4.y, a4.z, a4.w};
            const float bv[4] = {b4.x, b4.y, b4.z, b4.w};
            #pragma unroll
            for (int i = 0; i < 4; ++i)
                #pragma unroll
                for (int j = 0; j < 4; ++j)
                    acc[i][j] += av[i] * bv[j];
        }
        __syncthreads();
    }
    #pragma unroll
    for (int i = 0; i < 4; ++i) {
        const int m = m0 + ty * 4 + i;
        #pragma unroll
        for (int j = 0; j < 4; ++j) {
            const int n = n0 + tx * 4 + j;
            C[(size_t)m * OD + n] = acc[i][j] + bias[n];
        }
    }
}

extern "C" void kernel_launch(void* const* d_in, const int* in_sizes, int n_in,
                              void* d_out, int out_size, void* d_ws, size_t ws_size,
                              hipStream_t stream) {
    const float* X   = (const float*)d_in[0];
    const float* Wih = (const float*)d_in[1];
    const float* Whh = (const float*)d_in[2];
    const float* bih = (const float*)d_in[3];
    const float* bhh = (const float*)d_in[4];
    const float* Wfc = (const float*)d_in[5];
    const float* bfc = (const float*)d_in[6];
    float* out = (float*)d_out;

    float* hs  = (float*)d_ws;                                   // 64 MB
    u32*  vals = (u32*)((char*)d_ws + (size_t)T_LEN * H * 4);    // 2*PSTRIDE*4 ~ 139 KB

    // parity0: h_0 = 0.0, lap 0 (valid for t=0). parity1: 0x01 bytes -> lap 1
    // blocks t=1 consumers until the real h_1 arrives.
    hipMemsetAsync(vals, 0x00, (size_t)PSTRIDE * 4, stream);
    hipMemsetAsync(vals + PSTRIDE, 0x01, (size_t)PSTRIDE * 4, stream);

    void* args[] = { (void*)&X, (void*)&Wih, (void*)&Whh, (void*)&bih,
                     (void*)&bhh, (void*)&hs, (void*)&vals };
    hipError_t e = hipLaunchCooperativeKernel((const void*)gru_rec_kernel,
                                              dim3(NWG), dim3(256), args, 0, stream);
    if (e != hipSuccess) {
        gru_rec_kernel<<<dim3(NWG), dim3(256), 0, stream>>>(X, Wih, Whh, bih, bhh, hs, vals);
    }

    dim3 fgrid(OD / BN, T_LEN / BM);
    fc_kernel<<<fgrid, dim3(256), 0, stream>>>(hs, Wfc, bfc, out);
}